// Round 6
// baseline (805.806 us; speedup 1.0000x reference)
//
#include <hip/hip_runtime.h>
#include <hip/hip_bf16.h>
#include <math.h>

typedef __hip_bfloat16 bf16t;

#define DI 1024
#define NSTATE 16
#define TLEN 2048
#define NCHUNK 32
#define CLEN 64
#define LOG2E 1.4426950408889634f

__device__ __forceinline__ float b2f(bf16t v) { return __bfloat162float(v); }

// runtime-dtype load for INPUTS: f=1 -> fp32, f=0 -> bf16
__device__ __forceinline__ float load_any(const void* s, long i, int f) {
  return f ? ((const float*)s)[i] : b2f(((const bf16t*)s)[i]);
}

// ---------------- dtype detect: flag=1 if inputs are fp32, 0 if bf16
__global__ __launch_bounds__(256) void detect_dtype(const unsigned int* __restrict__ x,
                                                    int* __restrict__ flag) {
  __shared__ int cnt;
  if (threadIdx.x == 0) cnt = 0;
  __syncthreads();
  unsigned int w = x[threadIdx.x];
  int e = (w >> 7) & 0xFF;  // exponent field of low half viewed as bf16
  if (e >= 110 && e <= 135) atomicAdd(&cnt, 1);
  __syncthreads();
  if (threadIdx.x == 0) *flag = (cnt < 128) ? 1 : 0;
}

// ---------------- VALU GEMM: C[M,N] = A[M,K] * B[N,K]^T, fp32 accumulate, fp32 out
// MODE 0: plain. MODE 1: +bias then softplus.
// aMode/bMode: 0=bf16, 1=fp32, 2=use *flag
template <int MODE>
__global__ __launch_bounds__(256) void gemm_valu(
    const void* __restrict__ A, const void* __restrict__ B,
    float* __restrict__ outF, const void* __restrict__ bias,
    int K, int lda, int ldb, int ldc, int aMode, int bMode, const int* __restrict__ flag)
{
  __shared__ float As[64][17];
  __shared__ float Bs[64][17];
  int tid = threadIdx.x;
  int tx = tid & 15, ty = tid >> 4;
  int bm = blockIdx.x * 64, bn = blockIdx.y * 64;
  int f = *flag;
  int da = (aMode == 2) ? f : aMode;
  int db = (bMode == 2) ? f : bMode;
  float acc[4][4] = {};
  for (int kk = 0; kk < K; kk += 16) {
#pragma unroll
    for (int q = 0; q < 4; q++) {
      int e = tid * 4 + q;
      int r = e >> 4, c = e & 15;
      As[r][c] = load_any(A, (long)(bm + r) * lda + kk + c, da);
      Bs[r][c] = load_any(B, (long)(bn + r) * ldb + kk + c, db);
    }
    __syncthreads();
#pragma unroll
    for (int k = 0; k < 16; k++) {
      float av[4], bv[4];
#pragma unroll
      for (int i = 0; i < 4; i++) av[i] = As[ty * 4 + i][k];
#pragma unroll
      for (int j = 0; j < 4; j++) bv[j] = Bs[tx * 4 + j][k];
#pragma unroll
      for (int i = 0; i < 4; i++)
#pragma unroll
        for (int j = 0; j < 4; j++) acc[i][j] += av[i] * bv[j];
    }
    __syncthreads();
  }
#pragma unroll
  for (int i = 0; i < 4; i++)
#pragma unroll
    for (int j = 0; j < 4; j++) {
      int m = bm + ty * 4 + i, n = bn + tx * 4 + j;
      float v = acc[i][j];
      if (MODE == 1) {
        v += load_any(bias, n, f);
        v = (v > 20.f) ? v : log1pf(expf(v));
      }
      outF[(size_t)m * ldc + n] = v;
    }
}

// ---------------- depthwise causal conv(K=4) + SiLU  (fp32 in/out)
__global__ __launch_bounds__(256) void conv_silu(
    const float* __restrict__ proj, const void* __restrict__ cw,
    const void* __restrict__ cb, float* __restrict__ xt, const int* __restrict__ flag)
{
  int f = *flag;
  int idx = blockIdx.x * 256 + threadIdx.x;
  int d = idx & (DI - 1);
  int row = idx >> 10;
  int t = row & (TLEN - 1);
  float acc = load_any(cb, d, f);
#pragma unroll
  for (int k = 0; k < 4; k++) {
    int ts = t - 3 + k;
    if (ts >= 0) acc += load_any(cw, d * 4 + k, f) * proj[(size_t)(row - 3 + k) * 2048 + d];
  }
  xt[idx] = acc / (1.f + expf(-acc));
}

// ---------------- scan pass 1: per-chunk transfer product P and local state S
__global__ __launch_bounds__(256) void scan_pass1(
    const float* __restrict__ dt, const float* __restrict__ xt,
    const float* __restrict__ ssm, const void* __restrict__ alog,
    float* __restrict__ P, float* __restrict__ S, const int* __restrict__ flag)
{
  int f = *flag;
  int tid = threadIdx.x, blk = blockIdx.x;
  int c = blk & 31, dblk = (blk >> 5) & 3, b = blk >> 7;
  int d = dblk * 256 + tid;
  float A2[NSTATE], st[NSTATE], Pp[NSTATE];
#pragma unroll
  for (int n = 0; n < NSTATE; n++) {
    A2[n] = -expf(load_any(alog, d * NSTATE + n, f)) * LOG2E;
    st[n] = 0.f; Pp[n] = 1.f;
  }
  int t0 = c * CLEN;
  for (int tt = 0; tt < CLEN; tt++) {
    int row = b * TLEN + t0 + tt;
    float dtv = dt[(size_t)row * DI + d];
    float xv = xt[(size_t)row * DI + d];
    float dx = dtv * xv;
#pragma unroll
    for (int n = 0; n < NSTATE; n++) {
      float e = exp2f(dtv * A2[n]);
      st[n] = e * st[n] + dx * ssm[(size_t)row * 64 + 32 + n];
      Pp[n] *= e;
    }
  }
  size_t base = ((size_t)(b * NCHUNK + c) * NSTATE) * DI + d;
#pragma unroll
  for (int n = 0; n < NSTATE; n++) {
    P[base + (size_t)n * DI] = Pp[n];
    S[base + (size_t)n * DI] = st[n];
  }
}

// ---------------- scan pass 2: combine chunk boundaries
__global__ __launch_bounds__(256) void scan_pass2(
    const float* __restrict__ P, const float* __restrict__ S, float* __restrict__ Sin)
{
  int idx = blockIdx.x * 256 + threadIdx.x;  // 0..2047
  int b = idx >> 10, d = idx & (DI - 1);
  float s[NSTATE];
#pragma unroll
  for (int n = 0; n < NSTATE; n++) s[n] = 0.f;
  for (int c = 0; c < NCHUNK; c++) {
    size_t base = ((size_t)(b * NCHUNK + c) * NSTATE) * DI + d;
#pragma unroll
    for (int n = 0; n < NSTATE; n++) {
      Sin[base + (size_t)n * DI] = s[n];
      s[n] = P[base + (size_t)n * DI] * s[n] + S[base + (size_t)n * DI];
    }
  }
}

// ---------------- scan pass 3: full scan + D-skip + gating (y may alias dt!)
__global__ __launch_bounds__(256) void scan_pass3(
    const float* __restrict__ dt, const float* __restrict__ xt,
    const float* __restrict__ ssm, const void* __restrict__ alog,
    const float* __restrict__ Sin, const float* __restrict__ proj,
    const void* __restrict__ Dvec, float* __restrict__ y, const int* __restrict__ flag)
{
  int f = *flag;
  int tid = threadIdx.x, blk = blockIdx.x;
  int c = blk & 31, dblk = (blk >> 5) & 3, b = blk >> 7;
  int d = dblk * 256 + tid;
  float A2[NSTATE], st[NSTATE];
  size_t base = ((size_t)(b * NCHUNK + c) * NSTATE) * DI + d;
#pragma unroll
  for (int n = 0; n < NSTATE; n++) {
    A2[n] = -expf(load_any(alog, d * NSTATE + n, f)) * LOG2E;
    st[n] = Sin[base + (size_t)n * DI];
  }
  float Dd = load_any(Dvec, d, f);
  int t0 = c * CLEN;
  for (int tt = 0; tt < CLEN; tt++) {
    int row = b * TLEN + t0 + tt;
    float dtv = dt[(size_t)row * DI + d];   // read BEFORE y write (same slot, same thread)
    float xv = xt[(size_t)row * DI + d];
    float dx = dtv * xv;
    float yv = 0.f;
#pragma unroll
    for (int n = 0; n < NSTATE; n++) {
      float e = exp2f(dtv * A2[n]);
      st[n] = e * st[n] + dx * ssm[(size_t)row * 64 + 32 + n];
      yv += st[n] * ssm[(size_t)row * 64 + 48 + n];
    }
    float g = proj[(size_t)row * 2048 + 1024 + d];
    float sig = 1.f / (1.f + expf(-g));
    y[(size_t)row * DI + d] = (yv + xv * Dd) * (g * sig);
  }
}

extern "C" void kernel_launch(void* const* d_in, const int* in_sizes, int n_in,
                              void* d_out, int out_size, void* d_ws, size_t ws_size,
                              hipStream_t stream) {
  const void* x    = d_in[0];   // [2,2048,512]
  const void* w1   = d_in[1];   // [2048,512]
  const void* cw   = d_in[2];   // [1024,1,4]
  const void* cb   = d_in[3];   // [1024]
  const void* xw   = d_in[4];   // [64,1024]
  const void* dtw  = d_in[5];   // [1024,32]
  const void* dtb  = d_in[6];   // [1024]
  const void* alog = d_in[7];   // [1024,16]
  const void* Dv   = d_in[8];   // [1024]
  const void* w3   = d_in[9];   // [512,1024]

  char* ws = (char*)d_ws;
  int*   flag = (int*)ws;              ws += 256;
  float* proj = (float*)ws;            ws += (size_t)4096 * 2048 * 4;   // 33.55 MB
  float* xt   = (float*)ws;            ws += (size_t)4096 * 1024 * 4;   // 16.78 MB
  float* ssm  = (float*)ws;            ws += (size_t)4096 * 64 * 4;     // 1.05 MB
  float* dtf  = (float*)ws;            ws += (size_t)4096 * 1024 * 4;   // 16.78 MB (y aliases)
  float* P    = (float*)ws;            ws += (size_t)2 * 32 * 16 * 1024 * 4;  // 4.19 MB
  float* S    = (float*)ws;            ws += (size_t)2 * 32 * 16 * 1024 * 4;
  float* Sin  = (float*)ws;            ws += (size_t)2 * 32 * 16 * 1024 * 4;
  float* ybuf = dtf;  // alias: pass3 reads dt[row,d] then writes y[row,d], same thread
  // total ~80.8 MB

  detect_dtype<<<1, 256, 0, stream>>>((const unsigned int*)x, flag);
  // in_proj: [4096,512] x [2048,512]^T -> proj fp32 [4096,2048]
  gemm_valu<0><<<dim3(64, 32), 256, 0, stream>>>(x, w1, proj, nullptr,
                                                 512, 512, 512, 2048, 2, 2, flag);
  // depthwise conv + silu -> xt fp32 [4096,1024]
  conv_silu<<<dim3(16384), 256, 0, stream>>>(proj, cw, cb, xt, flag);
  // x_proj: [4096,1024] x [64,1024]^T -> ssm fp32 [4096,64]
  gemm_valu<0><<<dim3(64, 1), 256, 0, stream>>>(xt, xw, ssm, nullptr,
                                                1024, 1024, 1024, 64, 1, 2, flag);
  // dt_proj + bias + softplus: [4096,32] x [1024,32]^T -> dtf fp32 [4096,1024]
  gemm_valu<1><<<dim3(64, 16), 256, 0, stream>>>(ssm, dtw, dtf, dtb,
                                                 32, 64, 32, 1024, 1, 2, flag);
  // chunked linear-recurrence scan + gating -> ybuf fp32 [4096,1024]
  scan_pass1<<<dim3(256), 256, 0, stream>>>(dtf, xt, ssm, alog, P, S, flag);
  scan_pass2<<<dim3(8), 256, 0, stream>>>(P, S, Sin);
  scan_pass3<<<dim3(256), 256, 0, stream>>>(dtf, xt, ssm, alog, Sin, proj, Dv, ybuf, flag);
  // out_proj: [4096,1024] x [512,1024]^T -> d_out fp32 [4096,512]
  gemm_valu<0><<<dim3(64, 8), 256, 0, stream>>>(ybuf, w3, (float*)d_out, nullptr,
                                                1024, 1024, 1024, 512, 1, 2, flag);
}

// Round 7
// 417.672 us; speedup vs baseline: 1.9293x; 1.9293x over previous
//
#include <hip/hip_runtime.h>
#include <hip/hip_bf16.h>
#include <math.h>

typedef __hip_bfloat16 bf16t;
typedef __attribute__((ext_vector_type(8))) short short8;
typedef __attribute__((ext_vector_type(4))) float f32x4;

#define DI 1024
#define NSTATE 16
#define TLEN 2048
#define NCHUNK 32
#define CLEN 64
#define LOG2E 1.4426950408889634f

__device__ __forceinline__ float b2f(bf16t v) { return __bfloat162float(v); }
__device__ __forceinline__ bf16t f2b(float v) { return __float2bfloat16(v); }
__device__ __forceinline__ float softplusf(float v) { return (v > 20.f) ? v : log1pf(expf(v)); }

// runtime-dtype load for RAW INPUTS: f=1 -> fp32, f=0 -> bf16
__device__ __forceinline__ float load_any(const void* s, long i, int f) {
  return f ? ((const float*)s)[i] : b2f(((const bf16t*)s)[i]);
}

__device__ __forceinline__ void async16(const void* g, void* l) {
  __builtin_amdgcn_global_load_lds(
      (const __attribute__((address_space(1))) unsigned int*)g,
      (__attribute__((address_space(3))) unsigned int*)l, 16, 0, 0);
}

// ---------------- dtype detect: flag=1 if inputs are fp32, 0 if bf16
__global__ __launch_bounds__(256) void detect_dtype(const unsigned int* __restrict__ x,
                                                    int* __restrict__ flag) {
  __shared__ int cnt;
  if (threadIdx.x == 0) cnt = 0;
  __syncthreads();
  unsigned int w = x[threadIdx.x];
  int e = (w >> 7) & 0xFF;
  if (e >= 110 && e <= 135) atomicAdd(&cnt, 1);
  __syncthreads();
  if (threadIdx.x == 0) *flag = (cnt < 128) ? 1 : 0;
}

// ---------------- hi/lo split cast of the 4 GEMM matrices
// big region (aliased over P/S/Sin): x[0,2097152) w1[2097152,3145728)
// small region (persistent): xw[0,65536) w3[65536,589824)
__global__ __launch_bounds__(256) void cast_hilo(
    const void* __restrict__ x, const void* __restrict__ w1,
    const void* __restrict__ xw, const void* __restrict__ w3,
    short* __restrict__ bigH, short* __restrict__ bigL,
    short* __restrict__ smallH, short* __restrict__ smallL,
    const int* __restrict__ flag) {
  int i = blockIdx.x * 256 + threadIdx.x;   // 0 .. 3735552
  int f = *flag;
  float v; short *dh, *dl; int o;
  if (i < 3145728) {
    v = (i < 2097152) ? load_any(x, i, f) : load_any(w1, i - 2097152, f);
    dh = bigH; dl = bigL; o = i;
  } else {
    int j = i - 3145728;
    v = (j < 65536) ? load_any(xw, j, f) : load_any(w3, j - 65536, f);
    dh = smallH; dl = smallL; o = j;
  }
  bf16t h = f2b(v);
  dh[o] = *(short*)&h;
  bf16t l = f2b(v - b2f(h));
  dl[o] = *(short*)&l;
}

// ---------------- split-bf16 MFMA GEMM: C[M,N] (fp32) = A[M,K] * B[N,K]^T
// A,B given as bf16 hi/lo pairs; C = Ah*Bh + Ah*Bl + Al*Bh (fp32 accumulate)
template <int BM>
__global__ __launch_bounds__(256) void gemm_split(
    const short* __restrict__ Ah, const short* __restrict__ Al,
    const short* __restrict__ Bh, const short* __restrict__ Bl,
    float* __restrict__ C, int K, int lda, int ldb, int ldc)
{
  constexpr int NF = BM / 32;
  __shared__ __align__(16) short lAh[BM * 32], lAl[BM * 32], lBh[BM * 32], lBl[BM * 32];
  int tid = threadIdx.x;
  int lane = tid & 63, wave = tid >> 6;
  int bm = blockIdx.x * BM, bn = blockIdx.y * BM;
  int wm = (wave & 1) * (BM / 2), wn = (wave >> 1) * (BM / 2);
  f32x4 acc[NF][NF] = {};
  int r0 = tid >> 2, kp = (tid & 3) * 8;
  const short* pAh = Ah + (size_t)(bm + r0) * lda + kp;
  const short* pAl = Al + (size_t)(bm + r0) * lda + kp;
  const short* pBh = Bh + (size_t)(bn + r0) * ldb + kp;
  const short* pBl = Bl + (size_t)(bn + r0) * ldb + kp;
  int ldsOff = tid * 8;   // tid*16 bytes, wave-contiguous (matches lane*16 DMA scatter)
  int la = (lane & 15) * 32 + (lane >> 4) * 8;
  for (int kk = 0; kk < K; kk += 32) {
#pragma unroll
    for (int s = 0; s < BM / 64; s++) {
      async16(pAh + kk + (size_t)s * 64 * lda, &lAh[ldsOff + s * 64 * 32]);
      async16(pAl + kk + (size_t)s * 64 * lda, &lAl[ldsOff + s * 64 * 32]);
      async16(pBh + kk + (size_t)s * 64 * ldb, &lBh[ldsOff + s * 64 * 32]);
      async16(pBl + kk + (size_t)s * 64 * ldb, &lBl[ldsOff + s * 64 * 32]);
    }
    asm volatile("s_waitcnt vmcnt(0)" ::: "memory");
    __syncthreads();
    short8 ah[NF], al[NF], bh[NF], bl[NF];
#pragma unroll
    for (int i = 0; i < NF; i++) {
      ah[i] = *(const short8*)&lAh[(wm + i * 16) * 32 + la];
      al[i] = *(const short8*)&lAl[(wm + i * 16) * 32 + la];
      bh[i] = *(const short8*)&lBh[(wn + i * 16) * 32 + la];
      bl[i] = *(const short8*)&lBl[(wn + i * 16) * 32 + la];
    }
#pragma unroll
    for (int i = 0; i < NF; i++)
#pragma unroll
      for (int j = 0; j < NF; j++) {
        acc[i][j] = __builtin_amdgcn_mfma_f32_16x16x32_bf16(ah[i], bh[j], acc[i][j], 0, 0, 0);
        acc[i][j] = __builtin_amdgcn_mfma_f32_16x16x32_bf16(ah[i], bl[j], acc[i][j], 0, 0, 0);
        acc[i][j] = __builtin_amdgcn_mfma_f32_16x16x32_bf16(al[i], bh[j], acc[i][j], 0, 0, 0);
      }
    __syncthreads();
  }
  int rbase = (lane >> 4) * 4, ncol = lane & 15;
#pragma unroll
  for (int i = 0; i < NF; i++)
#pragma unroll
    for (int j = 0; j < NF; j++)
#pragma unroll
      for (int r = 0; r < 4; r++) {
        int m = bm + wm + i * 16 + rbase + r;
        int n = bn + wn + j * 16 + ncol;
        C[(size_t)m * ldc + n] = acc[i][j][r];
      }
}

// ---------------- depthwise causal conv(K=4) + SiLU -> xt as bf16 hi/lo pair
__global__ __launch_bounds__(256) void conv_silu(
    const float* __restrict__ proj, const void* __restrict__ cw,
    const void* __restrict__ cb, short* __restrict__ xh, short* __restrict__ xl,
    const int* __restrict__ flag)
{
  int f = *flag;
  int idx = blockIdx.x * 256 + threadIdx.x;
  int d = idx & (DI - 1);
  int row = idx >> 10;
  int t = row & (TLEN - 1);
  float acc = load_any(cb, d, f);
#pragma unroll
  for (int k = 0; k < 4; k++) {
    int ts = t - 3 + k;
    if (ts >= 0) acc += load_any(cw, d * 4 + k, f) * proj[(size_t)(row - 3 + k) * 2048 + d];
  }
  float s = acc / (1.f + expf(-acc));
  bf16t h = f2b(s);
  xh[idx] = *(short*)&h;
  bf16t l = f2b(s - b2f(h));
  xl[idx] = *(short*)&l;
}

// ---------------- scan pass 1: dt recompute + per-chunk P, S
__global__ __launch_bounds__(256) void scan_pass1(
    const short* __restrict__ xh, const short* __restrict__ xl,
    const float* __restrict__ ssm, const void* __restrict__ alog,
    const void* __restrict__ dtw, const void* __restrict__ dtb,
    float* __restrict__ P, float* __restrict__ S, const int* __restrict__ flag)
{
  int f = *flag;
  int tid = threadIdx.x, blk = blockIdx.x;
  int c = blk & 31, dblk = (blk >> 5) & 3, b = blk >> 7;
  int d = dblk * 256 + tid;
  float A2[NSTATE], st[NSTATE], Pp[NSTATE], wreg[32];
#pragma unroll
  for (int n = 0; n < NSTATE; n++) {
    A2[n] = -expf(load_any(alog, d * NSTATE + n, f)) * LOG2E;
    st[n] = 0.f; Pp[n] = 1.f;
  }
#pragma unroll
  for (int k = 0; k < 32; k++) wreg[k] = load_any(dtw, (long)d * 32 + k, f);
  float bias = load_any(dtb, d, f);
  int t0 = c * CLEN;
  for (int tt = 0; tt < CLEN; tt++) {
    int row = b * TLEN + t0 + tt;
    float raw = bias;
#pragma unroll
    for (int k = 0; k < 32; k++) raw += ssm[(size_t)row * 64 + k] * wreg[k];
    float dtv = softplusf(raw);
    long xi = (size_t)row * DI + d;
    float xv = b2f(*(const bf16t*)&xh[xi]) + b2f(*(const bf16t*)&xl[xi]);
    float dx = dtv * xv;
#pragma unroll
    for (int n = 0; n < NSTATE; n++) {
      float e = exp2f(dtv * A2[n]);
      st[n] = e * st[n] + dx * ssm[(size_t)row * 64 + 32 + n];
      Pp[n] *= e;
    }
  }
  size_t base = ((size_t)(b * NCHUNK + c) * NSTATE) * DI + d;
#pragma unroll
  for (int n = 0; n < NSTATE; n++) {
    P[base + (size_t)n * DI] = Pp[n];
    S[base + (size_t)n * DI] = st[n];
  }
}

// ---------------- scan pass 2: combine chunk boundaries
__global__ __launch_bounds__(256) void scan_pass2(
    const float* __restrict__ P, const float* __restrict__ S, float* __restrict__ Sin)
{
  int idx = blockIdx.x * 256 + threadIdx.x;  // 0..2047
  int b = idx >> 10, d = idx & (DI - 1);
  float s[NSTATE];
#pragma unroll
  for (int n = 0; n < NSTATE; n++) s[n] = 0.f;
  for (int c = 0; c < NCHUNK; c++) {
    size_t base = ((size_t)(b * NCHUNK + c) * NSTATE) * DI + d;
#pragma unroll
    for (int n = 0; n < NSTATE; n++) {
      Sin[base + (size_t)n * DI] = s[n];
      s[n] = P[base + (size_t)n * DI] * s[n] + S[base + (size_t)n * DI];
    }
  }
}

// ---------------- scan pass 3: full scan + D-skip + gating -> y hi/lo pair
__global__ __launch_bounds__(256) void scan_pass3(
    const short* __restrict__ xh, const short* __restrict__ xl,
    const float* __restrict__ ssm, const void* __restrict__ alog,
    const void* __restrict__ dtw, const void* __restrict__ dtb,
    const float* __restrict__ Sin, const float* __restrict__ proj,
    const void* __restrict__ Dvec, short* __restrict__ yh, short* __restrict__ yl,
    const int* __restrict__ flag)
{
  int f = *flag;
  int tid = threadIdx.x, blk = blockIdx.x;
  int c = blk & 31, dblk = (blk >> 5) & 3, b = blk >> 7;
  int d = dblk * 256 + tid;
  float A2[NSTATE], st[NSTATE], wreg[32];
  size_t base = ((size_t)(b * NCHUNK + c) * NSTATE) * DI + d;
#pragma unroll
  for (int n = 0; n < NSTATE; n++) {
    A2[n] = -expf(load_any(alog, d * NSTATE + n, f)) * LOG2E;
    st[n] = Sin[base + (size_t)n * DI];
  }
#pragma unroll
  for (int k = 0; k < 32; k++) wreg[k] = load_any(dtw, (long)d * 32 + k, f);
  float bias = load_any(dtb, d, f);
  float Dd = load_any(Dvec, d, f);
  int t0 = c * CLEN;
  for (int tt = 0; tt < CLEN; tt++) {
    int row = b * TLEN + t0 + tt;
    float raw = bias;
#pragma unroll
    for (int k = 0; k < 32; k++) raw += ssm[(size_t)row * 64 + k] * wreg[k];
    float dtv = softplusf(raw);
    long xi = (size_t)row * DI + d;
    float xv = b2f(*(const bf16t*)&xh[xi]) + b2f(*(const bf16t*)&xl[xi]);
    float dx = dtv * xv;
    float yv = 0.f;
#pragma unroll
    for (int n = 0; n < NSTATE; n++) {
      float e = exp2f(dtv * A2[n]);
      st[n] = e * st[n] + dx * ssm[(size_t)row * 64 + 32 + n];
      yv += st[n] * ssm[(size_t)row * 64 + 48 + n];
    }
    float g = proj[(size_t)row * 2048 + 1024 + d];
    float sig = 1.f / (1.f + expf(-g));
    float out = (yv + xv * Dd) * (g * sig);
    bf16t h = f2b(out);
    yh[xi] = *(short*)&h;
    bf16t l = f2b(out - b2f(h));
    yl[xi] = *(short*)&l;
  }
}

extern "C" void kernel_launch(void* const* d_in, const int* in_sizes, int n_in,
                              void* d_out, int out_size, void* d_ws, size_t ws_size,
                              hipStream_t stream) {
  const void* x    = d_in[0];   // [2,2048,512]
  const void* w1   = d_in[1];   // [2048,512]
  const void* cw   = d_in[2];   // [1024,1,4]
  const void* cb   = d_in[3];   // [1024]
  const void* xw   = d_in[4];   // [64,1024]
  const void* dtw  = d_in[5];   // [1024,32]
  const void* dtb  = d_in[6];   // [1024]
  const void* alog = d_in[7];   // [1024,16]
  const void* Dv   = d_in[8];   // [1024]
  const void* w3   = d_in[9];   // [512,1024]

  char* ws = (char*)d_ws;
  int*   flag = (int*)ws;              ws += 256;
  float* proj = (float*)ws;            ws += (size_t)4096 * 2048 * 4;   // 33.55 MB
  short* xt_h = (short*)ws;            ws += (size_t)4096 * 1024 * 2;   // 8.39 MB
  short* xt_l = (short*)ws;            ws += (size_t)4096 * 1024 * 2;
  float* ssm  = (float*)ws;            ws += (size_t)4096 * 64 * 4;     // 1.05 MB
  short* y_h  = (short*)ws;            ws += (size_t)4096 * 1024 * 2;   // 8.39 MB
  short* y_l  = (short*)ws;            ws += (size_t)4096 * 1024 * 2;
  char*  R    = ws;                    ws += (size_t)3 * 4194304;       // 12.58 MB shared
  short* smH  = (short*)ws;            ws += (size_t)589824 * 2;        // 1.18 MB
  short* smL  = (short*)ws;            ws += (size_t)589824 * 2;
  // total ~83.1 MB

  // R region: cast staging (x,w1 hi/lo) early, P/S/Sin later (in_proj done first)
  short* bigH = (short*)R;                       // 6.29 MB: x @0, w1 @2097152
  short* bigL = (short*)(R + 6291456);
  float* P    = (float*)R;
  float* S    = (float*)(R + 4194304);
  float* Sin  = (float*)(R + 8388608);

  detect_dtype<<<1, 256, 0, stream>>>((const unsigned int*)x, flag);
  cast_hilo<<<dim3(14592), 256, 0, stream>>>(x, w1, xw, w3, bigH, bigL, smH, smL, flag);
  // in_proj: [4096,512] x [2048,512]^T -> proj fp32 [4096,2048]
  gemm_split<128><<<dim3(32, 16), 256, 0, stream>>>(
      bigH, bigL, bigH + 2097152, bigL + 2097152, proj, 512, 512, 512, 2048);
  // depthwise conv + silu -> xt hi/lo
  conv_silu<<<dim3(16384), 256, 0, stream>>>(proj, cw, cb, xt_h, xt_l, flag);
  // x_proj: [4096,1024] x [64,1024]^T -> ssm fp32 [4096,64]
  gemm_split<64><<<dim3(64, 1), 256, 0, stream>>>(
      xt_h, xt_l, smH, smL, ssm, 1024, 1024, 1024, 64);
  // chunked linear-recurrence scan (dt_proj fused inside) -> y hi/lo
  scan_pass1<<<dim3(256), 256, 0, stream>>>(xt_h, xt_l, ssm, alog, dtw, dtb, P, S, flag);
  scan_pass2<<<dim3(8), 256, 0, stream>>>(P, S, Sin);
  scan_pass3<<<dim3(256), 256, 0, stream>>>(xt_h, xt_l, ssm, alog, dtw, dtb, Sin, proj,
                                            Dv, y_h, y_l, flag);
  // out_proj: [4096,1024] x [512,1024]^T -> d_out fp32 [4096,512]
  gemm_split<128><<<dim3(32, 4), 256, 0, stream>>>(
      y_h, y_l, smH + 65536, smL + 65536, (float*)d_out, 1024, 1024, 1024, 512);
}